// Round 11
// baseline (277.771 us; speedup 1.0000x reference)
//
#include <hip/hip_runtime.h>
#include <stdint.h>

typedef __bf16 bf16x8 __attribute__((ext_vector_type(8)));
typedef float f32x4 __attribute__((ext_vector_type(4)));
typedef uint16_t u16;
typedef uint32_t u32;
typedef u16 u16x8 __attribute__((ext_vector_type(8)));

#define NSTEP 63   // 2*32-1 diagonal steps

// ---- workspace layout (bytes) ----
#define IMG_SK_BYTES (128ull*NSTEP*4096ull*2ull)
#define WPACK_OFF    IMG_SK_BYTES
#define BIAS_OFF     (WPACK_OFF + 512ull*384ull*2ull)
#define TMP_OFF      (BIAS_OFF + 2048ull)

// ---- helpers ----
__device__ __forceinline__ u16 f2bf(float f) {
  u32 u = __builtin_bit_cast(u32, f);
  return (u16)((u + 0x7fffu + ((u >> 16) & 1u)) >> 16);   // RNE
}
__device__ __forceinline__ float bf2f(u16 h) {
  u32 u = ((u32)h) << 16;
  return __builtin_bit_cast(float, u);
}
__device__ __forceinline__ float sigf(float x) {
  float e = __builtin_amdgcn_exp2f(-1.442695041f * x);
  return __builtin_amdgcn_rcpf(1.0f + e);
}
__device__ __forceinline__ float tanhf_fast(float x) {
  x = fminf(fmaxf(x, -20.f), 20.f);       // clamp: avoid inf-inf NaN
  float e = __builtin_amdgcn_exp2f(2.885390082f * x);
  return (e - 1.0f) * __builtin_amdgcn_rcpf(e + 1.0f);
}
__device__ __forceinline__ void gload_lds16(const void* g, char* smem, u32 lds_off) {
  __builtin_amdgcn_global_load_lds(
      (const __attribute__((address_space(1))) uint32_t*)g,
      (__attribute__((address_space(3))) uint32_t*)(smem + lds_off), 16, 0, 0);
}
__device__ __forceinline__ bf16x8 ldsv(const char* smem, u32 off) {
  return *reinterpret_cast<const bf16x8*>(smem + off);    // ds_read_b128
}

// =====================================================================
// Kernel 1: pre-skew image (R1/R3/R4/R10-passing verbatim).
// =====================================================================
__global__ __launch_bounds__(256) void k_prepack_img(
    const float* __restrict__ image, u16* __restrict__ img_sk) {
  __shared__ float tile[128 * 33];
  const int b = blockIdx.x >> 5, n = blockIdx.x & 31;
  const int tid = threadIdx.x;
  for (int rep = 0; rep < 16; ++rep) {
    int idx = rep * 256 + tid;
    int c = idx >> 5, col = idx & 31;
    tile[c * 33 + col] = image[(((b * 128 + c) * 32 + n) << 5) + col];
  }
  __syncthreads();
  const int m = n & 7;
  for (int rep = 0; rep < 4; ++rep) {
    int idx = rep * 256 + tid;
    if (idx < NSTEP * 16) {
      int t = idx >> 4, six = idx & 15;
      bool valid = (t >= n) && (t < n + 32);
      u16x8 v;
      #pragma unroll
      for (int j = 0; j < 8; ++j) {
        int c = ((six ^ m) << 3) | j;              // inverse of read-side XOR swizzle
        v[j] = valid ? f2bf(tile[c * 33 + (t - n)]) : (u16)0;
      }
      *reinterpret_cast<u16x8*>(img_sk + (size_t)(b * NSTEP + t) * 4096 + n * 128 + six * 8) = v;
    }
  }
}

// =====================================================================
// Kernel 2: pack W, 8-wave geometry (R1/R4/R10-passing verbatim).
// =====================================================================
__global__ __launch_bounds__(256) void k_prepack_w(
    const float* __restrict__ stos_w, const float* __restrict__ itos_w,
    u16* __restrict__ wp) {
  int pos = blockIdx.x * 256 + threadIdx.x;        // [w][mt][kk][lane][j]
  int j = pos & 7, l = (pos >> 3) & 63;
  int kk = (pos >> 9) % 12;
  int mtw = pos / 6144;
  int mt = mtw & 3, w = mtw >> 2;
  int r16 = l & 15;
  int q = r16 & 3, p = r16 >> 2;
  int c = w * 16 + mt * 4 + p;
  int o = q * 128 + c;
  int k = kk * 32 + (l >> 4) * 8 + j;
  float v;
  if (k < 128)       v = stos_w[o * 256 + k * 2 + 0];
  else if (k < 256)  v = stos_w[o * 256 + (k - 128) * 2 + 1];
  else               v = itos_w[o * 128 + (k - 256)];
  wp[pos] = f2bf(v);
}

__global__ void k_prepack_bias(const float* __restrict__ itos_b,
                               const float* __restrict__ stos_b,
                               float* __restrict__ bp) {
  int R = blockIdx.x * 256 + threadIdx.x;
  if (R >= 512) return;
  int q = R & 3, p = (R >> 2) & 3, mt = (R >> 4) & 3, w = R >> 6;
  int o = q * 128 + (w * 16 + mt * 4 + p);
  bp[R] = itos_b[o] + stos_b[o];
}

// =====================================================================
// Kernel 3: diagonal-LSTM scan — R10's passing kernel with two deltas:
//   (1) hbuf DOUBLE-BUFFERED -> single __syncthreads per step
//   (2) MFMA ladder split by N-half: acc[*][0] finishes before the nt=1
//       ladder starts, so nt=0 activations overlap nt=1 MFMAs (VALU||MFMA)
// LDS map (static 114688 B):
//   [0,8448) hbuf0 | [8448,16896) hbuf1 | [16896,18944) bias
//   [32768,49152) imgbuf x2 (8KB each)  | [49152,114688) A-frags kk=10,11
// =====================================================================
__global__ __attribute__((amdgpu_waves_per_eu(2, 2)))
__launch_bounds__(512, 2) void k_scan(
    const u16* __restrict__ img_sk, const u16* __restrict__ wpack,
    const float* __restrict__ biasp, const float* __restrict__ h0,
    const float* __restrict__ c0, u16* __restrict__ tmp) {
  __shared__ char smem[114688];
  const int b = blockIdx.x;
  const int tid = threadIdx.x;
  const int w = tid >> 6, lane = tid & 63;
  const int p = (lane >> 4) & 3, n0 = lane & 15;

  // ---- load A fragments kk 0..9 into registers (160 regs) ----
  bf16x8 aw[4][10];
  #pragma unroll
  for (int mt = 0; mt < 4; ++mt)
    #pragma unroll
    for (int kk = 0; kk < 10; ++kk)
      aw[mt][kk] = *reinterpret_cast<const bf16x8*>(
          wpack + (size_t)(((w * 4 + mt) * 12 + kk) * 64 + lane) * 8);
  // kk=10,11 A-frags -> LDS (once; W constant)
  #pragma unroll
  for (int mt = 0; mt < 4; ++mt) {
    gload_lds16(wpack + (size_t)(((w * 4 + mt) * 12 + 10) * 64 + lane) * 8,
                smem, 49152u + (u32)w * 8192u + (u32)mt * 2048u);
    gload_lds16(wpack + (size_t)(((w * 4 + mt) * 12 + 11) * 64 + lane) * 8,
                smem, 49152u + (u32)w * 8192u + (u32)mt * 2048u + 1024u);
  }
  // preload imgbuf[0] (t=0)
  const u16* img_base = img_sk + (size_t)b * NSTEP * 4096;
  gload_lds16(img_base + (u32)tid * 8, smem, 32768u + (u32)w * 1024u);
  // bias -> LDS
  ((float*)(smem + 16896))[tid] = biasp[tid & 511];
  // hbuf0 init: row 0 = zeros, rows 1..32 = h0 (swizzled) — R10 formula
  for (int idx = tid; idx < 33 * 128; idx += 512) {
    int row = idx >> 7, c = idx & 127;
    u16 v = (row == 0) ? (u16)0 : f2bf(h0[c * 32 + (row - 1)]);
    u32 a = (u32)(row << 8) | (u32)((((c >> 3) ^ (row & 7)) << 4) | ((c & 7) << 1));
    *(u16*)(smem + a) = v;
  }
  // hbuf1 row 0 = zeros (rows 1..32 written at step 0)
  for (int idx = tid; idx < 128; idx += 512) {
    int c = idx;
    u32 a = 8448u + (u32)(((c >> 3) << 4) | ((c & 7) << 1));
    *(u16*)(smem + a) = (u16)0;
  }
  // c state in registers
  float cst[4][2];
  #pragma unroll
  for (int mt = 0; mt < 4; ++mt)
    #pragma unroll
    for (int nt = 0; nt < 2; ++nt)
      cst[mt][nt] = c0[(w * 16 + mt * 4 + p) * 32 + (nt * 16 + n0)];

  // per-lane swizzle bases (R10-passing verbatim; composed additively with
  // buffer bases: Ls/Lh <= 8447 < 8448 region size, ib regions 8KB-disjoint)
  const int na = n0, nb = n0 + 16;
  const u32 Ls0 = (u32)(na << 8) ^ (u32)(p << 4) ^ (u32)((na & 7) << 4);
  const u32 Ls1 = (u32)(nb << 8) ^ (u32)(p << 4) ^ (u32)((nb & 7) << 4);
  const u32 Lh0 = (u32)((na + 1) << 8) ^ (u32)(p << 4) ^ (u32)(((na + 1) & 7) << 4);
  const u32 Lh1 = (u32)((nb + 1) << 8) ^ (u32)(p << 4) ^ (u32)(((nb + 1) & 7) << 4);
  const u32 Lw0 = (u32)((na + 1) << 8) ^ (u32)(((na + 1) & 7) << 4) ^ (u32)(w << 5) ^ (u32)(p << 1);
  const u32 Lw1 = (u32)((nb + 1) << 8) ^ (u32)(((nb + 1) & 7) << 4) ^ (u32)(w << 5) ^ (u32)(p << 1);
  const u32 tmpidx = (u32)((w * 16 + p) * 32 + n0);     // + mt*128 + nt*16
  u16* tmpb = tmp + (size_t)b * NSTEP * 4096;

  __syncthreads();

  f32x4 acc[4][2];
  u16 hb[8];

  #pragma unroll 1
  for (int t = 0; t < NSTEP; ++t) {
    // deferred tmp stores for step t-1 (long done by this step's barrier)
    if (t) {
      #pragma unroll
      for (int mt = 0; mt < 4; ++mt)
        #pragma unroll
        for (int nt = 0; nt < 2; ++nt)
          tmpb[(size_t)(t - 1) * 4096 + tmpidx + mt * 128 + nt * 16] = hb[mt * 2 + nt];
    }
    // prefetch next image column into the other imgbuf
    if (t < NSTEP - 1)
      gload_lds16(img_base + (size_t)(t + 1) * 4096 + (u32)tid * 8,
                  smem, 32768u + (u32)(((t + 1) & 1) << 13) + (u32)w * 1024u);
    // acc = bias
    #pragma unroll
    for (int mt = 0; mt < 4; ++mt) {
      f32x4 bv = *reinterpret_cast<const f32x4*>(smem + 16896 + ((w * 64 + mt * 16 + p * 4) << 2));
      acc[mt][0] = bv; acc[mt][1] = bv;
    }

    const u32 hbb = (u32)((t & 1) ? 8448u : 0u);          // read buffer base
    const u32 ib  = 32768u + (u32)((t & 1) << 13);

    // ---- ladder, nt=0 half: 12 kk x 4 mt = 48 MFMAs; acc[*][0] final ----
    #pragma unroll
    for (int kk = 0; kk < 12; ++kk) {
      bf16x8 b0;
      if (kk < 4)      b0 = ldsv(smem, hbb + (Ls0 ^ (u32)(kk << 6)));
      else if (kk < 8) b0 = ldsv(smem, hbb + (Lh0 ^ (u32)((kk - 4) << 6)));
      else             b0 = ldsv(smem, ib + (Ls0 ^ (u32)((kk - 8) << 6)));
      #pragma unroll
      for (int mt = 0; mt < 4; ++mt) {
        bf16x8 a = (kk < 10) ? aw[mt][kk]
                             : ldsv(smem, 49152u + (u32)w * 8192u + (u32)mt * 2048u
                                        + (u32)((kk - 10) << 10) + (u32)lane * 16u);
        acc[mt][0] = __builtin_amdgcn_mfma_f32_16x16x32_bf16(a, b0, acc[mt][0], 0, 0, 0);
      }
    }
    // ---- ladder, nt=1 half (nt=0 activations overlap these MFMAs) ----
    #pragma unroll
    for (int kk = 0; kk < 12; ++kk) {
      bf16x8 b1;
      if (kk < 4)      b1 = ldsv(smem, hbb + (Ls1 ^ (u32)(kk << 6)));
      else if (kk < 8) b1 = ldsv(smem, hbb + (Lh1 ^ (u32)((kk - 4) << 6)));
      else             b1 = ldsv(smem, ib + (Ls1 ^ (u32)((kk - 8) << 6)));
      #pragma unroll
      for (int mt = 0; mt < 4; ++mt) {
        bf16x8 a = (kk < 10) ? aw[mt][kk]
                             : ldsv(smem, 49152u + (u32)w * 8192u + (u32)mt * 2048u
                                        + (u32)((kk - 10) << 10) + (u32)lane * 16u);
        acc[mt][1] = __builtin_amdgcn_mfma_f32_16x16x32_bf16(a, b1, acc[mt][1], 0, 0, 0);
      }
    }
    // ---- activations (nt=0 slice schedulable into the nt=1 ladder) ----
    #pragma unroll
    for (int nt = 0; nt < 2; ++nt)
      #pragma unroll
      for (int mt = 0; mt < 4; ++mt) {
        f32x4 g4 = acc[mt][nt];
        float si = sigf(g4[0]);
        float tg = tanhf_fast(g4[1]);
        float sf = sigf(g4[2]);
        float so = sigf(g4[3]);
        float cp = cst[mt][nt];
        cst[mt][nt] = sf * cp + si * tg;   // c_new
        hb[mt * 2 + nt] = f2bf(cp * so);   // h_new = c_prev * sig(o)  (per reference)
      }
    // write h(t) into the OTHER hbuf (rows n+1); reads this step used hbb
    {
      const u32 hwb = (u32)((t & 1) ? 0u : 8448u);
      #pragma unroll
      for (int mt = 0; mt < 4; ++mt)
        #pragma unroll
        for (int nt = 0; nt < 2; ++nt) {
          u32 a = hwb + ((nt ? Lw1 : Lw0) ^ (u32)((mt >= 2) ? 16u : 0u) ^ (u32)((mt & 1) << 3));
          *(u16*)(smem + a) = hb[mt * 2 + nt];
        }
    }
    __syncthreads();   // single barrier: h(t) + img(t+1) visible for step t+1
  }
  // final step's tmp stores
  #pragma unroll
  for (int mt = 0; mt < 4; ++mt)
    #pragma unroll
    for (int nt = 0; nt < 2; ++nt)
      tmpb[(size_t)(NSTEP - 1) * 4096 + tmpidx + mt * 128 + nt * 16] = hb[mt * 2 + nt];
}

// =====================================================================
// Kernel 4: unskew-transpose tmp -> out (R3/R4/R10-passing verbatim).
// =====================================================================
__global__ __launch_bounds__(256) void k_unskew(
    const u16* __restrict__ tmp, float* __restrict__ out) {
  __shared__ float tile[8192];                 // [cl][s][j] = cl*1024+s*32+j
  const int b = blockIdx.x >> 4, c8 = blockIdx.x & 15;
  const int tid = threadIdx.x;
  const int cl = tid >> 5, s = tid & 31;
  const u16* tb = tmp + (size_t)b * NSTEP * 4096 + (u32)(c8 * 256 + cl * 32 + s);
  for (int t = 0; t < NSTEP; ++t) {
    u16 v = tb[t * 4096];
    int j = t - s;
    if ((unsigned)j < 32u) tile[cl * 1024 + s * 32 + j] = bf2f(v);
  }
  __syncthreads();
  float* op = out + (size_t)b * 131072 + (u32)(c8 * 8192);
  #pragma unroll
  for (int rep = 0; rep < 8; ++rep)
    *(f32x4*)(op + rep * 1024 + tid * 4) = *(const f32x4*)(tile + rep * 1024 + tid * 4);
}

// =====================================================================
extern "C" void kernel_launch(void* const* d_in, const int* in_sizes, int n_in,
                              void* d_out, int out_size, void* d_ws, size_t ws_size,
                              hipStream_t stream) {
  const float* image  = (const float*)d_in[0];
  const float* itos_w = (const float*)d_in[1];
  const float* itos_b = (const float*)d_in[2];
  const float* stos_w = (const float*)d_in[3];
  const float* stos_b = (const float*)d_in[4];
  const float* h0     = (const float*)d_in[5];
  const float* c0     = (const float*)d_in[6];
  (void)in_sizes; (void)n_in; (void)out_size; (void)ws_size;

  char* ws = (char*)d_ws;
  u16*   img_sk = (u16*)(ws);
  u16*   wpack  = (u16*)(ws + WPACK_OFF);
  float* biasp  = (float*)(ws + BIAS_OFF);
  u16*   tmp    = (u16*)(ws + TMP_OFF);

  k_prepack_img <<<4096, 256, 0, stream>>>(image, img_sk);
  k_prepack_w   <<<768, 256, 0, stream>>>(stos_w, itos_w, wpack);
  k_prepack_bias<<<2, 256, 0, stream>>>(itos_b, stos_b, biasp);
  k_scan        <<<128, 512, 0, stream>>>(img_sk, wpack, biasp, h0, c0, tmp);
  k_unskew      <<<2048, 256, 0, stream>>>(tmp, (float*)d_out);
}

// Round 12
// 249.058 us; speedup vs baseline: 1.1153x; 1.1153x over previous
//
#include <hip/hip_runtime.h>
#include <stdint.h>

typedef __bf16 bf16x8 __attribute__((ext_vector_type(8)));
typedef float f32x4 __attribute__((ext_vector_type(4)));
typedef uint16_t u16;
typedef uint32_t u32;
typedef u16 u16x8 __attribute__((ext_vector_type(8)));

#define NSTEP 63   // 2*32-1 diagonal steps

// ---- workspace layout (bytes) ----
#define IMG_SK_BYTES (128ull*NSTEP*4096ull*2ull)
#define WPACK_OFF    IMG_SK_BYTES
#define BIAS_OFF     (WPACK_OFF + 512ull*384ull*2ull)
#define TMP_OFF      (BIAS_OFF + 2048ull)

// ---- helpers ----
__device__ __forceinline__ u16 f2bf(float f) {
  u32 u = __builtin_bit_cast(u32, f);
  return (u16)((u + 0x7fffu + ((u >> 16) & 1u)) >> 16);   // RNE
}
__device__ __forceinline__ float bf2f(u16 h) {
  u32 u = ((u32)h) << 16;
  return __builtin_bit_cast(float, u);
}
__device__ __forceinline__ float sigf(float x) {
  float e = __builtin_amdgcn_exp2f(-1.442695041f * x);
  return __builtin_amdgcn_rcpf(1.0f + e);
}
__device__ __forceinline__ float tanhf_fast(float x) {
  x = fminf(fmaxf(x, -20.f), 20.f);       // clamp: avoid inf-inf NaN
  float e = __builtin_amdgcn_exp2f(2.885390082f * x);
  return (e - 1.0f) * __builtin_amdgcn_rcpf(e + 1.0f);
}
__device__ __forceinline__ void gload_lds16(const void* g, char* smem, u32 lds_off) {
  __builtin_amdgcn_global_load_lds(
      (const __attribute__((address_space(1))) uint32_t*)g,
      (__attribute__((address_space(3))) uint32_t*)(smem + lds_off), 16, 0, 0);
}
__device__ __forceinline__ bf16x8 ldsv(const char* smem, u32 off) {
  return *reinterpret_cast<const bf16x8*>(smem + off);    // ds_read_b128
}

// =====================================================================
// Kernel 1: pre-skew image (R1/R3/R4/R10/R11-passing verbatim).
// =====================================================================
__global__ __launch_bounds__(256) void k_prepack_img(
    const float* __restrict__ image, u16* __restrict__ img_sk) {
  __shared__ float tile[128 * 33];
  const int b = blockIdx.x >> 5, n = blockIdx.x & 31;
  const int tid = threadIdx.x;
  for (int rep = 0; rep < 16; ++rep) {
    int idx = rep * 256 + tid;
    int c = idx >> 5, col = idx & 31;
    tile[c * 33 + col] = image[(((b * 128 + c) * 32 + n) << 5) + col];
  }
  __syncthreads();
  const int m = n & 7;
  for (int rep = 0; rep < 4; ++rep) {
    int idx = rep * 256 + tid;
    if (idx < NSTEP * 16) {
      int t = idx >> 4, six = idx & 15;
      bool valid = (t >= n) && (t < n + 32);
      u16x8 v;
      #pragma unroll
      for (int j = 0; j < 8; ++j) {
        int c = ((six ^ m) << 3) | j;              // inverse of read-side XOR swizzle
        v[j] = valid ? f2bf(tile[c * 33 + (t - n)]) : (u16)0;
      }
      *reinterpret_cast<u16x8*>(img_sk + (size_t)(b * NSTEP + t) * 4096 + n * 128 + six * 8) = v;
    }
  }
}

// =====================================================================
// Kernel 2: pack W, 8-wave geometry (R1/R4/R10/R11-passing verbatim).
// =====================================================================
__global__ __launch_bounds__(256) void k_prepack_w(
    const float* __restrict__ stos_w, const float* __restrict__ itos_w,
    u16* __restrict__ wp) {
  int pos = blockIdx.x * 256 + threadIdx.x;        // [w][mt][kk][lane][j]
  int j = pos & 7, l = (pos >> 3) & 63;
  int kk = (pos >> 9) % 12;
  int mtw = pos / 6144;
  int mt = mtw & 3, w = mtw >> 2;
  int r16 = l & 15;
  int q = r16 & 3, p = r16 >> 2;
  int c = w * 16 + mt * 4 + p;
  int o = q * 128 + c;
  int k = kk * 32 + (l >> 4) * 8 + j;
  float v;
  if (k < 128)       v = stos_w[o * 256 + k * 2 + 0];
  else if (k < 256)  v = stos_w[o * 256 + (k - 128) * 2 + 1];
  else               v = itos_w[o * 128 + (k - 256)];
  wp[pos] = f2bf(v);
}

__global__ void k_prepack_bias(const float* __restrict__ itos_b,
                               const float* __restrict__ stos_b,
                               float* __restrict__ bp) {
  int R = blockIdx.x * 256 + threadIdx.x;
  if (R >= 512) return;
  int q = R & 3, p = (R >> 2) & 3, mt = (R >> 4) & 3, w = R >> 6;
  int o = q * 128 + (w * 16 + mt * 4 + p);
  bp[R] = itos_b[o] + stos_b[o];
}

// =====================================================================
// Kernel 3: diagonal-LSTM scan.
//   Base: R10's passing interleaved ladder (b0/b1 together, A read once).
//   Delta 1 (R11-verified): hbuf double-buffer -> ONE barrier per step.
//   Delta 2: bias held in 4 VGPR f32x4 (no per-step LDS bias reads).
// LDS map (static 114688 B, R11-verified):
//   [0,8448) hbuf0 | [8448,16896) hbuf1 | [16896,18944) bias(init only)
//   [32768,49152) imgbuf x2 (8KB each)  | [49152,114688) A-frags kk=10,11
// =====================================================================
__global__ __attribute__((amdgpu_waves_per_eu(2, 2)))
__launch_bounds__(512, 2) void k_scan(
    const u16* __restrict__ img_sk, const u16* __restrict__ wpack,
    const float* __restrict__ biasp, const float* __restrict__ h0,
    const float* __restrict__ c0, u16* __restrict__ tmp) {
  __shared__ char smem[114688];
  const int b = blockIdx.x;
  const int tid = threadIdx.x;
  const int w = tid >> 6, lane = tid & 63;
  const int p = (lane >> 4) & 3, n0 = lane & 15;

  // ---- load A fragments kk 0..9 into registers (160 regs) ----
  bf16x8 aw[4][10];
  #pragma unroll
  for (int mt = 0; mt < 4; ++mt)
    #pragma unroll
    for (int kk = 0; kk < 10; ++kk)
      aw[mt][kk] = *reinterpret_cast<const bf16x8*>(
          wpack + (size_t)(((w * 4 + mt) * 12 + kk) * 64 + lane) * 8);
  // kk=10,11 A-frags -> LDS (once; W constant)
  #pragma unroll
  for (int mt = 0; mt < 4; ++mt) {
    gload_lds16(wpack + (size_t)(((w * 4 + mt) * 12 + 10) * 64 + lane) * 8,
                smem, 49152u + (u32)w * 8192u + (u32)mt * 2048u);
    gload_lds16(wpack + (size_t)(((w * 4 + mt) * 12 + 11) * 64 + lane) * 8,
                smem, 49152u + (u32)w * 8192u + (u32)mt * 2048u + 1024u);
  }
  // preload imgbuf[0] (t=0)
  const u16* img_base = img_sk + (size_t)b * NSTEP * 4096;
  gload_lds16(img_base + (u32)tid * 8, smem, 32768u + (u32)w * 1024u);
  // bias -> LDS (staging only; consumed into registers below)
  ((float*)(smem + 16896))[tid] = biasp[tid & 511];
  // hbuf0 init: row 0 = zeros, rows 1..32 = h0 (swizzled) — R10/R11 formula
  for (int idx = tid; idx < 33 * 128; idx += 512) {
    int row = idx >> 7, c = idx & 127;
    u16 v = (row == 0) ? (u16)0 : f2bf(h0[c * 32 + (row - 1)]);
    u32 a = (u32)(row << 8) | (u32)((((c >> 3) ^ (row & 7)) << 4) | ((c & 7) << 1));
    *(u16*)(smem + a) = v;
  }
  // hbuf1 row 0 = zeros (rows 1..32 written at step 0)
  for (int idx = tid; idx < 128; idx += 512) {
    int c = idx;
    u32 a = 8448u + (u32)(((c >> 3) << 4) | ((c & 7) << 1));
    *(u16*)(smem + a) = (u16)0;
  }
  // c state in registers
  float cst[4][2];
  #pragma unroll
  for (int mt = 0; mt < 4; ++mt)
    #pragma unroll
    for (int nt = 0; nt < 2; ++nt)
      cst[mt][nt] = c0[(w * 16 + mt * 4 + p) * 32 + (nt * 16 + n0)];

  // per-lane swizzle bases (R10/R11-passing verbatim)
  const int na = n0, nb = n0 + 16;
  const u32 Ls0 = (u32)(na << 8) ^ (u32)(p << 4) ^ (u32)((na & 7) << 4);
  const u32 Ls1 = (u32)(nb << 8) ^ (u32)(p << 4) ^ (u32)((nb & 7) << 4);
  const u32 Lh0 = (u32)((na + 1) << 8) ^ (u32)(p << 4) ^ (u32)(((na + 1) & 7) << 4);
  const u32 Lh1 = (u32)((nb + 1) << 8) ^ (u32)(p << 4) ^ (u32)(((nb + 1) & 7) << 4);
  const u32 Lw0 = (u32)((na + 1) << 8) ^ (u32)(((na + 1) & 7) << 4) ^ (u32)(w << 5) ^ (u32)(p << 1);
  const u32 Lw1 = (u32)((nb + 1) << 8) ^ (u32)(((nb + 1) & 7) << 4) ^ (u32)(w << 5) ^ (u32)(p << 1);
  const u32 tmpidx = (u32)((w * 16 + p) * 32 + n0);     // + mt*128 + nt*16
  u16* tmpb = tmp + (size_t)b * NSTEP * 4096;

  __syncthreads();

  // bias into registers (once)
  f32x4 bias_r[4];
  #pragma unroll
  for (int mt = 0; mt < 4; ++mt)
    bias_r[mt] = *reinterpret_cast<const f32x4*>(smem + 16896 + ((w * 64 + mt * 16 + p * 4) << 2));

  f32x4 acc[4][2];
  u16 hb[8];

  #pragma unroll 1
  for (int t = 0; t < NSTEP; ++t) {
    // deferred tmp stores for step t-1
    if (t) {
      #pragma unroll
      for (int mt = 0; mt < 4; ++mt)
        #pragma unroll
        for (int nt = 0; nt < 2; ++nt)
          tmpb[(size_t)(t - 1) * 4096 + tmpidx + mt * 128 + nt * 16] = hb[mt * 2 + nt];
    }
    // prefetch next image column into the other imgbuf
    if (t < NSTEP - 1)
      gload_lds16(img_base + (size_t)(t + 1) * 4096 + (u32)tid * 8,
                  smem, 32768u + (u32)(((t + 1) & 1) << 13) + (u32)w * 1024u);
    // acc = bias (from registers)
    #pragma unroll
    for (int mt = 0; mt < 4; ++mt) {
      acc[mt][0] = bias_r[mt]; acc[mt][1] = bias_r[mt];
    }

    const u32 hbb = (u32)((t & 1) ? 8448u : 0u);          // hbuf read base
    const u32 ib  = 32768u + (u32)((t & 1) << 13);

    // ---- MFMA ladder (R10 interleaved form; A read once per (mt,kk)) ----
    #pragma unroll
    for (int kk = 0; kk < 12; ++kk) {
      bf16x8 b0, b1;
      if (kk < 4) {            // shifted h: hbuf row n
        b0 = ldsv(smem, hbb + (Ls0 ^ (u32)(kk << 6)));
        b1 = ldsv(smem, hbb + (Ls1 ^ (u32)(kk << 6)));
      } else if (kk < 8) {     // h: hbuf row n+1
        b0 = ldsv(smem, hbb + (Lh0 ^ (u32)((kk - 4) << 6)));
        b1 = ldsv(smem, hbb + (Lh1 ^ (u32)((kk - 4) << 6)));
      } else {                 // image column
        b0 = ldsv(smem, ib + (Ls0 ^ (u32)((kk - 8) << 6)));
        b1 = ldsv(smem, ib + (Ls1 ^ (u32)((kk - 8) << 6)));
      }
      #pragma unroll
      for (int mt = 0; mt < 4; ++mt) {
        bf16x8 a = (kk < 10) ? aw[mt][kk]
                             : ldsv(smem, 49152u + (u32)w * 8192u + (u32)mt * 2048u
                                        + (u32)((kk - 10) << 10) + (u32)lane * 16u);
        acc[mt][0] = __builtin_amdgcn_mfma_f32_16x16x32_bf16(a, b0, acc[mt][0], 0, 0, 0);
        acc[mt][1] = __builtin_amdgcn_mfma_f32_16x16x32_bf16(a, b1, acc[mt][1], 0, 0, 0);
      }
    }
    // ---- activations (regs j = i,g,f,o of one (c,s)) ----
    #pragma unroll
    for (int mt = 0; mt < 4; ++mt)
      #pragma unroll
      for (int nt = 0; nt < 2; ++nt) {
        f32x4 g4 = acc[mt][nt];
        float si = sigf(g4[0]);
        float tg = tanhf_fast(g4[1]);
        float sf = sigf(g4[2]);
        float so = sigf(g4[3]);
        float cp = cst[mt][nt];
        cst[mt][nt] = sf * cp + si * tg;   // c_new
        hb[mt * 2 + nt] = f2bf(cp * so);   // h_new = c_prev * sig(o)  (per reference)
      }
    // write h(t) into the OTHER hbuf (rows n+1); this step read from hbb
    {
      const u32 hwb = (u32)((t & 1) ? 0u : 8448u);
      #pragma unroll
      for (int mt = 0; mt < 4; ++mt)
        #pragma unroll
        for (int nt = 0; nt < 2; ++nt) {
          u32 a = hwb + ((nt ? Lw1 : Lw0) ^ (u32)((mt >= 2) ? 16u : 0u) ^ (u32)((mt & 1) << 3));
          *(u16*)(smem + a) = hb[mt * 2 + nt];
        }
    }
    __syncthreads();   // single barrier: h(t) + img(t+1) visible for step t+1
  }
  // final step's tmp stores
  #pragma unroll
  for (int mt = 0; mt < 4; ++mt)
    #pragma unroll
    for (int nt = 0; nt < 2; ++nt)
      tmpb[(size_t)(NSTEP - 1) * 4096 + tmpidx + mt * 128 + nt * 16] = hb[mt * 2 + nt];
}

// =====================================================================
// Kernel 4: unskew-transpose tmp -> out (R3/R4/R10/R11-passing verbatim).
// =====================================================================
__global__ __launch_bounds__(256) void k_unskew(
    const u16* __restrict__ tmp, float* __restrict__ out) {
  __shared__ float tile[8192];                 // [cl][s][j] = cl*1024+s*32+j
  const int b = blockIdx.x >> 4, c8 = blockIdx.x & 15;
  const int tid = threadIdx.x;
  const int cl = tid >> 5, s = tid & 31;
  const u16* tb = tmp + (size_t)b * NSTEP * 4096 + (u32)(c8 * 256 + cl * 32 + s);
  for (int t = 0; t < NSTEP; ++t) {
    u16 v = tb[t * 4096];
    int j = t - s;
    if ((unsigned)j < 32u) tile[cl * 1024 + s * 32 + j] = bf2f(v);
  }
  __syncthreads();
  float* op = out + (size_t)b * 131072 + (u32)(c8 * 8192);
  #pragma unroll
  for (int rep = 0; rep < 8; ++rep)
    *(f32x4*)(op + rep * 1024 + tid * 4) = *(const f32x4*)(tile + rep * 1024 + tid * 4);
}

// =====================================================================
extern "C" void kernel_launch(void* const* d_in, const int* in_sizes, int n_in,
                              void* d_out, int out_size, void* d_ws, size_t ws_size,
                              hipStream_t stream) {
  const float* image  = (const float*)d_in[0];
  const float* itos_w = (const float*)d_in[1];
  const float* itos_b = (const float*)d_in[2];
  const float* stos_w = (const float*)d_in[3];
  const float* stos_b = (const float*)d_in[4];
  const float* h0     = (const float*)d_in[5];
  const float* c0     = (const float*)d_in[6];
  (void)in_sizes; (void)n_in; (void)out_size; (void)ws_size;

  char* ws = (char*)d_ws;
  u16*   img_sk = (u16*)(ws);
  u16*   wpack  = (u16*)(ws + WPACK_OFF);
  float* biasp  = (float*)(ws + BIAS_OFF);
  u16*   tmp    = (u16*)(ws + TMP_OFF);

  k_prepack_img <<<4096, 256, 0, stream>>>(image, img_sk);
  k_prepack_w   <<<768, 256, 0, stream>>>(stos_w, itos_w, wpack);
  k_prepack_bias<<<2, 256, 0, stream>>>(itos_b, stos_b, biasp);
  k_scan        <<<128, 512, 0, stream>>>(img_sk, wpack, biasp, h0, c0, tmp);
  k_unskew      <<<2048, 256, 0, stream>>>(tmp, (float*)d_out);
}